// Round 1
// baseline (429.821 us; speedup 1.0000x reference)
//
#include <hip/hip_runtime.h>
#include <math.h>

// x[16][13][512][768] f32 -> out[16][13][3*768]
//   out[..., 0:768]     = sum over seq
//   out[..., 768:1536]  = std (ddof=1) over seq
//   out[..., 1536:2304] = max over seq
//
// Streaming reduction, HBM-bound (327 MB in, 1.9 MB out).
// Partitioning: each (batch,layer) row-block is split into 3 column-chunks
// of 256 floats (= 64 float4 = one full wave of 16B lanes -> every load is a
// single 1 KB coalesced transaction). Grid = 208*3 = 624 blocks so all 256
// CUs get 2-3 blocks; 8 waves/block, each wave reduces 64 rows, partials
// combined through LDS by wave 0. Plain (cached) loads: data is single-use,
// NT hint dropped to match the verified 6.3 TB/s float4-copy path.
#define BL      208             // 16*13
#define SEQ     512
#define HID     768
#define CHUNK_F 256             // floats per column-chunk
#define CHUNK_V 64              // float4 per column-chunk (= 1 wave)
#define NCHUNK  3               // HID / CHUNK_F
#define GROUPS  8               // row groups (one wave each)
#define ROWS    (SEQ / GROUPS)  // 64 rows per wave
#define TPB     (CHUNK_V * GROUPS) // 512 threads, 8 waves

typedef float f4v __attribute__((ext_vector_type(4)));

__global__ __launch_bounds__(TPB) void msm_fused(
    const float* __restrict__ x, float* __restrict__ out)
{
    // partials from waves 1..7: [stat][group-1][col]  (3*7*64*16 B = 21.5 KB)
    __shared__ f4v sh[3][GROUPS - 1][CHUNK_V];

    const int bl    = blockIdx.x / NCHUNK;
    const int chunk = blockIdx.x % NCHUNK;
    const int tid   = threadIdx.x;
    const int grp   = tid >> 6;      // 0..7  (= wave id)
    const int col   = tid & 63;      // 0..63 (float4 column within chunk)

    const f4v* p = (const f4v*)(x + (size_t)bl * SEQ * HID
                                  + (size_t)grp * ROWS * HID
                                  + (size_t)chunk * CHUNK_F) + col;

    float sx = 0.f, sy = 0.f, sz = 0.f, sw = 0.f;
    float qx = 0.f, qy = 0.f, qz = 0.f, qw = 0.f;
    float mx = -INFINITY, my = -INFINITY, mz = -INFINITY, mw = -INFINITY;

    #pragma unroll 8
    for (int i = 0; i < ROWS; ++i) {
        f4v v = p[(size_t)i * (HID / 4)];
        sx += v.x; sy += v.y; sz += v.z; sw += v.w;
        qx = fmaf(v.x, v.x, qx); qy = fmaf(v.y, v.y, qy);
        qz = fmaf(v.z, v.z, qz); qw = fmaf(v.w, v.w, qw);
        mx = fmaxf(mx, v.x); my = fmaxf(my, v.y);
        mz = fmaxf(mz, v.z); mw = fmaxf(mw, v.w);
    }

    if (grp > 0) {
        sh[0][grp - 1][col] = (f4v){sx, sy, sz, sw};
        sh[1][grp - 1][col] = (f4v){qx, qy, qz, qw};
        sh[2][grp - 1][col] = (f4v){mx, my, mz, mw};
    }
    __syncthreads();

    if (grp == 0) {
        #pragma unroll
        for (int g = 0; g < GROUPS - 1; ++g) {
            f4v s = sh[0][g][col];
            f4v q = sh[1][g][col];
            f4v m = sh[2][g][col];
            sx += s.x; sy += s.y; sz += s.z; sw += s.w;
            qx += q.x; qy += q.y; qz += q.z; qw += q.w;
            mx = fmaxf(mx, m.x); my = fmaxf(my, m.y);
            mz = fmaxf(mz, m.z); mw = fmaxf(mw, m.w);
        }

        const float invn  = 1.0f / (float)SEQ;
        const float invn1 = 1.0f / ((float)SEQ - 1.0f);

        float vx = fmaxf((qx - sx * sx * invn) * invn1, 0.f);
        float vy = fmaxf((qy - sy * sy * invn) * invn1, 0.f);
        float vz = fmaxf((qz - sz * sz * invn) * invn1, 0.f);
        float vw = fmaxf((qw - sw * sw * invn) * invn1, 0.f);

        f4v* ob = (f4v*)(out + (size_t)bl * 3 * HID + (size_t)chunk * CHUNK_F);
        ob[col]                    = (f4v){sx, sy, sz, sw};
        ob[(HID / 4) + col]        = (f4v){sqrtf(vx), sqrtf(vy), sqrtf(vz), sqrtf(vw)};
        ob[2 * (HID / 4) + col]    = (f4v){mx, my, mz, mw};
    }
}

extern "C" void kernel_launch(void* const* d_in, const int* in_sizes, int n_in,
                              void* d_out, int out_size, void* d_ws, size_t ws_size,
                              hipStream_t stream) {
    const float* x = (const float*)d_in[0];
    float* out = (float*)d_out;
    msm_fused<<<BL * NCHUNK, TPB, 0, stream>>>(x, out);
}

// Round 2
// 426.068 us; speedup vs baseline: 1.0088x; 1.0088x over previous
//
#include <hip/hip_runtime.h>
#include <math.h>

// x[16][13][512][768] f32 -> out[16][13][3*768]
//   out[..., 0:768]     = sum over seq
//   out[..., 768:1536]  = std (ddof=1) over seq
//   out[..., 1536:2304] = max over seq
//
// Streaming reduction, HBM-bound (327 MB in, 1.9 MB out).
// Geometry: 208 (batch,layer) x 3 column-chunks of 256 floats = 624 blocks.
// Each block: 1024 threads = 16 waves; each wave reduces 32 rows of its
// 256-float column-chunk with 64-lane float4 loads (1 KB per load instr,
// perfectly coalesced). 624 blocks x 16 waves / 256 CU = 39 waves/CU demand
// -> saturates the 32-waves/CU capacity (vs 19.5 in the previous version).
// __launch_bounds__(1024, 8) caps VGPRs at 64 so 2 blocks/CU fit.
// Cross-wave combine through LDS (45 KB/block), wave 0 finalizes + writes.
#define BL      208
#define SEQ     512
#define HID     768
#define NCHUNK  3
#define CHUNK_F 256             // floats per column-chunk
#define CHUNK_V 64              // float4 per column-chunk (= 64 lanes)
#define WAVES   16
#define TPB     (WAVES * 64)    // 1024
#define RPW     (SEQ / WAVES)   // 32 rows per wave

typedef float f4v __attribute__((ext_vector_type(4)));

__global__ __launch_bounds__(TPB, 8) void msm_fused(
    const float* __restrict__ x, float* __restrict__ out)
{
    // partials from waves 1..15: [stat][wave-1][lane]  (3*15*64*16 B = 45 KB)
    __shared__ f4v sh[3][WAVES - 1][CHUNK_V];

    const int bl    = blockIdx.x / NCHUNK;
    const int chunk = blockIdx.x % NCHUNK;
    const int wv    = threadIdx.x >> 6;   // 0..15
    const int lane  = threadIdx.x & 63;   // float4 column within chunk

    const f4v* p = (const f4v*)(x + (size_t)bl * SEQ * HID
                                  + (size_t)wv * RPW * HID
                                  + (size_t)chunk * CHUNK_F) + lane;

    float sx = 0.f, sy = 0.f, sz = 0.f, sw = 0.f;
    float qx = 0.f, qy = 0.f, qz = 0.f, qw = 0.f;
    float mx = -INFINITY, my = -INFINITY, mz = -INFINITY, mw = -INFINITY;

    #pragma unroll 8
    for (int i = 0; i < RPW; ++i) {
        f4v v = p[(size_t)i * (HID / 4)];
        sx += v.x; sy += v.y; sz += v.z; sw += v.w;
        qx = fmaf(v.x, v.x, qx); qy = fmaf(v.y, v.y, qy);
        qz = fmaf(v.z, v.z, qz); qw = fmaf(v.w, v.w, qw);
        mx = fmaxf(mx, v.x); my = fmaxf(my, v.y);
        mz = fmaxf(mz, v.z); mw = fmaxf(mw, v.w);
    }

    if (wv > 0) {
        sh[0][wv - 1][lane] = (f4v){sx, sy, sz, sw};
        sh[1][wv - 1][lane] = (f4v){qx, qy, qz, qw};
        sh[2][wv - 1][lane] = (f4v){mx, my, mz, mw};
    }
    __syncthreads();

    if (wv == 0) {
        #pragma unroll
        for (int g = 0; g < WAVES - 1; ++g) {
            f4v s = sh[0][g][lane];
            f4v q = sh[1][g][lane];
            f4v m = sh[2][g][lane];
            sx += s.x; sy += s.y; sz += s.z; sw += s.w;
            qx += q.x; qy += q.y; qz += q.z; qw += q.w;
            mx = fmaxf(mx, m.x); my = fmaxf(my, m.y);
            mz = fmaxf(mz, m.z); mw = fmaxf(mw, m.w);
        }

        const float invn  = 1.0f / (float)SEQ;
        const float invn1 = 1.0f / ((float)SEQ - 1.0f);

        float vx = fmaxf((qx - sx * sx * invn) * invn1, 0.f);
        float vy = fmaxf((qy - sy * sy * invn) * invn1, 0.f);
        float vz = fmaxf((qz - sz * sz * invn) * invn1, 0.f);
        float vw = fmaxf((qw - sw * sw * invn) * invn1, 0.f);

        f4v* ob = (f4v*)(out + (size_t)bl * 3 * HID + (size_t)chunk * CHUNK_F);
        ob[lane]                 = (f4v){sx, sy, sz, sw};
        ob[(HID / 4) + lane]     = (f4v){sqrtf(vx), sqrtf(vy), sqrtf(vz), sqrtf(vw)};
        ob[2 * (HID / 4) + lane] = (f4v){mx, my, mz, mw};
    }
}

extern "C" void kernel_launch(void* const* d_in, const int* in_sizes, int n_in,
                              void* d_out, int out_size, void* d_ws, size_t ws_size,
                              hipStream_t stream) {
    const float* x = (const float*)d_in[0];
    float* out = (float*)d_out;
    msm_fused<<<BL * NCHUNK, TPB, 0, stream>>>(x, out);
}